// Round 12
// baseline (205.197 us; speedup 1.0000x reference)
//
#include <hip/hip_runtime.h>
#include <stdint.h>

// lap = I - adj/k, adj = exact k-NN graph (incl. self) under euclidean
// distance with jax.lax.top_k tie-break (lower index wins).
//
// R11 structure: SPLIT selection from emission.
//   prep_kernel: pack (-2x,-2y,-2z,|p|^2) -> d_ws (bitwise-exact d2, R7-R10).
//   sel_kernel:  1 wave/row, 16 rows/block, 64KB LDS tile; dual sorted-top-5
//                chains + ballot binary search for the kth distance D; pass2
//                recomputes d2 and captures the row's 4096-bit adjacency mask
//                DIRECTLY from the ballots (word w = half of ballot(c=w>>1)),
//                512 B/row -> d_ws. Writes 8 MB total instead of 256 MB, so
//                the fused-kernel occupancy mystery (R4 40% vs R9 19.5% at
//                identical footprints) only touches ~half the work.
//   emit_kernel: fillBuffer-shaped grid-stride stream (no LDS, tiny VGPR):
//                nibble lookup + diagonal compare per float4; 256 MB at
//                ~6.5 TB/s (harness fill sustains 6.8-7.0 TB/s).
// Exactness: identical arithmetic to R8/R9/R10 (absmax 0); bad-case serial
// fallback preserved (P ~ 7e-4/row).

constexpr int Npts = 4096;
constexpr int BLK  = 1024;   // sel: 16 waves = 16 rows per block

typedef unsigned long long u64;

__device__ inline u64 u64min(u64 a, u64 b) { return a < b ? a : b; }

__device__ inline u64 wave_min64(u64 v) {
#pragma unroll
    for (int off = 1; off < 64; off <<= 1) {
        u64 o = __shfl_xor(v, off, 64);
        v = u64min(v, o);
    }
    return v;
}

__device__ inline unsigned wave_min32(unsigned v) {
#pragma unroll
    for (int off = 1; off < 64; off <<= 1) {
        unsigned o = __shfl_xor(v, off, 64);
        v = v < o ? v : o;
    }
    return v;
}

__device__ inline unsigned wave_max32(unsigned v) {
#pragma unroll
    for (int off = 1; off < 64; off <<= 1) {
        unsigned o = __shfl_xor(v, off, 64);
        v = v > o ? v : o;
    }
    return v;
}

// d2 from packed (m2x=-2x, m2y=-2y, m2z=-2z, sq); bitwise == reference.
__device__ inline float cand_d2(const float4 pj, float ax, float ay, float az,
                                float sqi) {
    const float u = __fadd_rn(__fadd_rn(__fmul_rn(pj.x, ax), __fmul_rn(pj.y, ay)),
                              __fmul_rn(pj.z, az));        // == -2*rn_dot exactly
    const float v = __fadd_rn(__fadd_rn(sqi, pj.w), u);    // rn(rn(si+sj)-2t)
    return fmaxf(v, 0.0f);   // >= +0.0 -> u32 bit order == float order
}

// branchless sorted insert of d into ascending quintuple (all read OLD values)
#define INSERT5(q0, q1, q2, q3, q4, d)                                  \
    {                                                                   \
        const float n4 = __builtin_amdgcn_fmed3f(q3, q4, d);            \
        const float n3 = __builtin_amdgcn_fmed3f(q2, q3, d);            \
        const float n2 = __builtin_amdgcn_fmed3f(q1, q2, d);            \
        const float n1 = __builtin_amdgcn_fmed3f(q0, q1, d);            \
        const float n0 = fminf(q0, d);                                  \
        q0 = n0; q1 = n1; q2 = n2; q3 = n3; q4 = n4;                    \
    }

__global__ __launch_bounds__(256) void prep_kernel(const float* __restrict__ x,
                                                   float4* __restrict__ p,
                                                   int total) {
    const int t = blockIdx.x * 256 + threadIdx.x;
    if (t >= total) return;
    const float bx = x[3 * t], by = x[3 * t + 1], bz = x[3 * t + 2];
    const float sq = __fadd_rn(__fadd_rn(__fmul_rn(bx, bx), __fmul_rn(by, by)),
                               __fmul_rn(bz, bz));
    p[t] = make_float4(-2.0f * bx, -2.0f * by, -2.0f * bz, sq);  // *2 exact
}

__global__ __launch_bounds__(BLK, 4) void sel_kernel(const float* __restrict__ x,
                                                     const float4* __restrict__ pts,
                                                     const int* __restrict__ kptr,
                                                     unsigned* __restrict__ mask) {
    __shared__ float4 pts4[Npts];   // EXACTLY 64 KB

    const int tid  = threadIdx.x;
    const int lane = tid & 63;
    const int wv   = tid >> 6;                         // 0..15
    const int b    = blockIdx.x >> 8;                  // 256 blocks per batch
    const int i    = ((blockIdx.x & 255) << 4) | wv;   // this wave's row (0..4095)

    int k = *kptr;
    if (k < 1) k = 1;
    if (k > Npts) k = Npts;

    // ---- stage packed points once per block ----
    const float4* pb = pts + (size_t)b * Npts;
#pragma unroll
    for (int s = 0; s < Npts / BLK; ++s)
        pts4[tid + BLK * s] = pb[tid + BLK * s];
    __syncthreads();

    const float* xb = x + (size_t)b * (Npts * 3);
    const float ax = xb[3 * i], ay = xb[3 * i + 1], az = xb[3 * i + 2];
    const float sqi = pts4[i].w;               // wave-uniform broadcast read
    const float INF_F = __uint_as_float(0x7f800000u);

    // ---- pass1: two independent sorted-top-5 chains (even / odd c) ----
    float a0 = INF_F, a1 = INF_F, a2 = INF_F, a3 = INF_F, a4 = INF_F;
    float f0 = INF_F, f1 = INF_F, f2 = INF_F, f3 = INF_F, f4 = INF_F;
#pragma unroll 4
    for (unsigned c = 0; c < 64; c += 2) {
        const float dA = cand_d2(pts4[(c << 6) | (unsigned)lane], ax, ay, az, sqi);
        const float dB = cand_d2(pts4[((c + 1) << 6) | (unsigned)lane], ax, ay, az, sqi);
        INSERT5(a0, a1, a2, a3, a4, dA);
        INSERT5(f0, f1, f2, f3, f4, dB);
    }
    // exact bitonic lower-half merge: 5 smallest of the union (multiset)
    const float e0 = fminf(a0, f4), e1 = fminf(a1, f3), e2 = fminf(a2, f2),
                e3 = fminf(a3, f1), e4 = fminf(a4, f0);
    const float fifth = fmaxf(fmaxf(fmaxf(e0, e1), fmaxf(e2, e3)), e4);
    const unsigned eb0 = __float_as_uint(e0), eb1 = __float_as_uint(e1),
                   eb2 = __float_as_uint(e2), eb3 = __float_as_uint(e3),
                   eb4 = __float_as_uint(e4);
    const unsigned mylo = __float_as_uint(fminf(a0, f0));   // lane's true min

    // ---- ballot binary search for D = bits of the kth smallest ----
    unsigned lo = wave_min32(mylo);                      // count(< lo) == 0 < k
    unsigned hi = (k <= 64) ? wave_max32(mylo) + 1u : 0x7f800001u;
    unsigned n_lt = 0;
    while (hi - lo > 1u) {
        const unsigned mid = (lo + hi) >> 1;
        const unsigned cnt = (unsigned)__popcll(__ballot(eb0 < mid)) +
                             (unsigned)__popcll(__ballot(eb1 < mid)) +
                             (unsigned)__popcll(__ballot(eb2 < mid)) +
                             (unsigned)__popcll(__ballot(eb3 < mid)) +
                             (unsigned)__popcll(__ballot(eb4 < mid));
        if (cnt < (unsigned)k) { lo = mid; n_lt = cnt; } else { hi = mid; }
    }
    // exact unless a lane's cache might hide entries <= D
    const bool bad = (__any(__float_as_uint(fifth) <= lo) != 0) || (k > 256);

    // ---- build the row's 4096-bit mask; lane owns words lane and lane+64 ----
    // word w covers candidates j = 32w..32w+31; j=(c<<6)|l -> w = 2c + (l>>5),
    // so word w = bits of lanes 32(w&1)..32(w&1)+31 from ballot at c = w>>1.
    unsigned w0 = 0, w1 = 0;
    const unsigned myc0 = (unsigned)lane >> 1;          // c for word `lane`
    const unsigned myc1 = 32u + ((unsigned)lane >> 1);  // c for word `lane+64`
    const unsigned mysh = ((unsigned)lane & 1u) << 5;   // which half of the ballot

    if (!bad) {
        u64 eqmask = 0;
#pragma unroll 8
        for (unsigned c = 0; c < 64; ++c) {
            const float d = cand_d2(pts4[(c << 6) | (unsigned)lane], ax, ay, az, sqi);
            const unsigned dbits = __float_as_uint(d);
            const u64 B = __ballot(dbits < lo);
            if (c == myc0) w0 = (unsigned)(B >> mysh);
            if (c == myc1) w1 = (unsigned)(B >> mysh);
            eqmask |= (u64)(dbits == lo) << c;
        }
        // pick (k - n_lt) lowest-j entries among dist == D (typically 1 round)
        int rem = k - (int)n_lt;
        while (rem > 0) {
            const unsigned myj = eqmask
                ? (((unsigned)(__ffsll((long long)eqmask) - 1) << 6) | (unsigned)lane)
                : 0xFFFFFFFFu;
            const unsigned mn = wave_min32(myj);
            if (mn == 0xFFFFFFFFu) break;    // safety (cannot happen when !bad)
            const unsigned word = mn >> 5, bit = mn & 31u;
            if (word == (unsigned)lane)       w0 |= 1u << bit;
            if (word == (unsigned)lane + 64u) w1 |= 1u << bit;
            if (myj == mn) eqmask &= eqmask - 1;           // winner pops its bit
            --rem;
        }
    } else {
        // ---- exact serial fallback: k rounds of wave-min over rescans ----
        u64 used = 0;
        for (int t = 0; t < k; ++t) {
            u64 best = ~0ull;
            for (unsigned c = 0; c < 64; ++c) {
                if (!((used >> c) & 1ull)) {
                    const unsigned j = (c << 6) | (unsigned)lane;
                    const float d = cand_d2(pts4[j], ax, ay, az, sqi);
                    best = u64min(best, ((u64)__float_as_uint(d) << 32) | j);
                }
            }
            const u64 m = wave_min64(best);
            if (m == ~0ull) break;
            const unsigned j = (unsigned)m;                // winner j, wave-uniform
            const unsigned word = j >> 5, bit = j & 31u;
            if (word == (unsigned)lane)       w0 |= 1u << bit;
            if (word == (unsigned)lane + 64u) w1 |= 1u << bit;
            if (best == m) used |= 1ull << (j >> 6);       // unique -> one winner
        }
    }

    // ---- store the 512B row mask (both stores coalesced) ----
    unsigned* mrow = mask + ((size_t)(b * Npts + i) << 7);   // 128 words/row
    mrow[lane]      = w0;
    mrow[lane + 64] = w1;
}

__global__ __launch_bounds__(256) void emit_kernel(const unsigned* __restrict__ mask,
                                                   const int* __restrict__ kptr,
                                                   float4* __restrict__ out,
                                                   int total4) {
    int k = *kptr;
    if (k < 1) k = 1;
    if (k > Npts) k = Npts;
    const float r = 1.0f / sqrtf((float)k);
    const float negrr = -__fmul_rn(r, r);    // -(dinv_i*dinv_j); deg == k exactly

    const int stride = gridDim.x * 256;
    for (int idx = blockIdx.x * 256 + threadIdx.x; idx < total4; idx += stride) {
        const int row = idx >> 10;                 // global row (0 .. B*N)
        const int c4  = idx & 1023;                // float4 within row
        const unsigned word = mask[((size_t)row << 7) + (c4 >> 3)];
        const unsigned nib  = (word >> ((c4 & 7) << 2)) & 0xFu;
        const int i  = row & (Npts - 1);           // row within batch
        const int j0 = c4 << 2;                    // element index of v.x
        float4 v;
        v.x = (nib & 1u) ? negrr : 0.0f;
        v.y = (nib & 2u) ? negrr : 0.0f;
        v.z = (nib & 4u) ? negrr : 0.0f;
        v.w = (nib & 8u) ? negrr : 0.0f;
        v.x = __fadd_rn(v.x, (j0 + 0 == i) ? 1.0f : 0.0f);
        v.y = __fadd_rn(v.y, (j0 + 1 == i) ? 1.0f : 0.0f);
        v.z = __fadd_rn(v.z, (j0 + 2 == i) ? 1.0f : 0.0f);
        v.w = __fadd_rn(v.w, (j0 + 3 == i) ? 1.0f : 0.0f);
        out[idx] = v;
    }
}

extern "C" void kernel_launch(void* const* d_in, const int* in_sizes, int n_in,
                              void* d_out, int out_size, void* d_ws, size_t ws_size,
                              hipStream_t stream) {
    const float* x    = (const float*)d_in[0];
    const int*   kptr = (const int*)d_in[1];
    float*       out  = (float*)d_out;
    const int total = in_sizes[0] / 3;               // B * Npts points
    const int B     = total / Npts;

    float4*   pts  = (float4*)d_ws;                              // 256 KB
    unsigned* mask = (unsigned*)((char*)d_ws + (1u << 20));      // 8 MB @ +1MB

    hipLaunchKernelGGL(prep_kernel, dim3((total + 255) / 256), dim3(256), 0, stream,
                       x, pts, total);
    hipLaunchKernelGGL(sel_kernel, dim3(B * (Npts / 16)), dim3(BLK), 0, stream,
                       x, pts, kptr, mask);
    const int total4 = B * Npts * (Npts / 4);
    hipLaunchKernelGGL(emit_kernel, dim3(2048), dim3(256), 0, stream,
                       mask, kptr, (float4*)out, total4);
}